// Round 10
// baseline (185.411 us; speedup 1.0000x reference)
//
#include <hip/hip_runtime.h>
#include <hip/hip_bf16.h>
#include <math.h>

// ---------------------------------------------------------------------------
// Expansion kernel.  Q-form fusion: out[b,uv] = sum_k Q[b,k]*LW2T[n(uv),k]
// Round 10: round-9 structure + two counter-directed fixes:
//  (1) A-plane LDS layout [kk][q][col][e] (was [kk][col][q][e]): per-lane
//      read offset = lane*16B, contiguous 1KB per wave-read.  Round-9 layout
//      had lanes striding 64B -> 4-way bank conflict on EVERY A ds_read
//      (SQ_LDS_BANK_CONFLICT 283k -> 4.73M between rounds 7 and 8/9).
//  (2) non-temporal out stores: each XCD streams ~13MB of output writes
//      through its 4MiB L2, evicting the 2.36MB B-half -> B re-reads hit L3
//      at ~500-900cy (measured ~900cy/load; FETCH=27MB proves not HBM).
//      NT stores (gfx950 'nt') bypass/no-allocate L2 so B stays resident.
// ---------------------------------------------------------------------------

typedef short bf16x8 __attribute__((ext_vector_type(8)));
typedef float f32x4 __attribute__((ext_vector_type(4)));

static __device__ __forceinline__ short f2bf(float f) {
  unsigned u = __builtin_bit_cast(unsigned, f);
  u = u + 0x7fffu + ((u >> 16) & 1u);   // round-to-nearest-even
  return (short)(u >> 16);
}

static __device__ __forceinline__ void st_nt(float v, float* p) {
  __builtin_nontemporal_store(v, p);
}

// ---- pre-pass 1: LW2 [64][36864] f32 -> LW2T bf16 [36864][64] ------------
__global__ void k_transpose(const float* __restrict__ lw2, short* __restrict__ lw2t) {
  __shared__ float tile[64][65];
  int n0 = blockIdx.x * 64;
  int t = threadIdx.x;
#pragma unroll
  for (int k = 0; k < 16; ++k) {
    int idx = k * 256 + t;
    int c = idx >> 6, j = idx & 63;
    tile[c][j] = lw2[(size_t)c * 36864 + n0 + j];
  }
  __syncthreads();
#pragma unroll
  for (int k = 0; k < 16; ++k) {
    int idx = k * 256 + t;
    int n = idx >> 6, c = idx & 63;
    lw2t[(size_t)(n0 + n) * 64 + c] = f2bf(tile[c][n]);
  }
}

// ---- pre-pass 2: packed bias matrices ------------------------------------
__global__ void k_bias(const float* __restrict__ bw2, const float* __restrict__ lb2,
                       const float* __restrict__ bb2,
                       short* __restrict__ bb00, short* __restrict__ bb11,
                       short* __restrict__ bb01, short* __restrict__ bb10) {
  int r = blockIdx.x * 256 + threadIdx.x;
  if (r < 1024) {
    int uv = r;
    for (int k = 0; k < 64; ++k) bb00[uv * 96 + k] = f2bf(bw2[k * 1280 + uv]);
    for (int w = 0; w < 16; ++w) bb00[uv * 96 + 64 + w] = f2bf(lb2[w * 1024 + uv]);
    bb00[uv * 96 + 80] = f2bf(bb2[uv]);
    for (int k = 81; k < 96; ++k) bb00[uv * 96 + k] = 0;
  } else if (r < 1280) {
    int uv = r - 1024;
    for (int k = 0; k < 64; ++k) bb11[uv * 96 + k] = f2bf(bw2[k * 1280 + 1024 + uv]);
    for (int w = 0; w < 16; ++w) bb11[uv * 96 + 64 + w] = f2bf(lb2[16384 + w * 256 + uv]);
    bb11[uv * 96 + 80] = f2bf(bb2[1024 + uv]);
    for (int k = 81; k < 96; ++k) bb11[uv * 96 + k] = 0;
  } else if (r < 1792) {
    int uv = r - 1280;
    for (int w = 0; w < 16; ++w) bb01[uv * 32 + w] = f2bf(lb2[20480 + w * 512 + uv]);
    for (int k = 16; k < 32; ++k) bb01[uv * 32 + k] = 0;
  } else if (r < 2304) {
    int uv = r - 1792;
    for (int w = 0; w < 16; ++w) bb10[uv * 32 + w] = f2bf(lb2[28672 + w * 512 + uv]);
    for (int k = 16; k < 32; ++k) bb10[uv * 32 + k] = 0;
  }
}

// ---- pre-pass 3: per-sample h, h2, x0, x1 --------------------------------
__global__ void k_samples(const float* __restrict__ feat, const float* __restrict__ ne,
                          const float* __restrict__ W0, const float* __restrict__ W1,
                          const float* __restrict__ lw1, const float* __restrict__ lb1,
                          const float* __restrict__ bw1, const float* __restrict__ bb1,
                          float* __restrict__ H, float* __restrict__ H2,
                          float* __restrict__ X0, float* __restrict__ X1) {
  int b = blockIdx.x;
  int t = threadIdx.x;               // 192 threads
  __shared__ float sne[128];
  __shared__ float sf[320];
  if (t < 128) sne[t] = ne[(size_t)b * 128 + t];
  for (int i = t; i < 320; i += 192) sf[i] = feat[(size_t)b * 320 + i];
  __syncthreads();
  if (t < 64) {
    float a = lb1[t];
    for (int k = 0; k < 128; ++k) a += sne[k] * lw1[k * 64 + t];
    H[(size_t)b * 64 + t] = a / (1.0f + expf(-a));
  } else if (t < 128) {
    int c = t - 64;
    float a = bb1[c];
    for (int k = 0; k < 128; ++k) a += sne[k] * bw1[k * 64 + c];
    H2[(size_t)b * 64 + c] = a / (1.0f + expf(-a));
  } else if (t < 144) {
    int v = t - 128;
    float a = 0.0f;
    for (int u = 0; u < 128; ++u) a += sf[u] * W0[u * 16 + v];
    X0[(size_t)b * 16 + v] = a * 0.08838834764831845f;  // 1/sqrt(128)
  } else {
    int idx = t - 144, v = idx / 3, j = idx % 3;        // idx < 48
    float a = 0.0f;
    for (int u = 0; u < 64; ++u) a += sf[128 + u * 3 + j] * W1[u * 16 + v];
    X1[(size_t)b * 48 + v * 3 + j] = a * 0.125f;        // 1/sqrt(64)
  }
}

// ---- main kernel ----------------------------------------------------------
// Phase A helper: 2 sample-group Q-planes (stride 16384 shorts), NBIAS bias.
// Depth-4 B register pipeline; kk loop fully unrolled -> static buffer idx.
template <int N, int NOFF, int NSTR, int NBIAS, int BBW>
static __device__ __forceinline__ void mmA2(
    const short* __restrict__ LW2T, const short* __restrict__ BB,
    const short* __restrict__ sQp, const short* __restrict__ sAbp,
    int uvbase, int col, int q, f32x4 (&acc)[2][N]) {
  const short* lw = LW2T + (size_t)(NOFF + uvbase + col) * 64;
  const int aoff = (q * 16 + col) * 8;   // = lane*8 shorts: conflict-free
  auto bptr = [&](int kk, int i) -> const bf16x8* {
    return (const bf16x8*)(lw + ((size_t)(kk >> 1) * NSTR + i * 16) * 64 +
                           ((kk & 1) * 32 + q * 8));
  };
  bf16x8 B[4][N];
#pragma unroll
  for (int d = 0; d < 4; ++d)
#pragma unroll
    for (int i = 0; i < N; ++i) B[d][i] = *bptr(d, i);
#pragma unroll
  for (int kk = 0; kk < 32; ++kk) {
    const int d = kk & 3;
    const bf16x8 A0 = *(const bf16x8*)(sQp + kk * 512 + aoff);
    const bf16x8 A1 = *(const bf16x8*)(sQp + 16384 + kk * 512 + aoff);
#pragma unroll
    for (int i = 0; i < N; ++i) {
      acc[0][i] = __builtin_amdgcn_mfma_f32_16x16x32_bf16(A0, B[d][i], acc[0][i], 0, 0, 0);
      acc[1][i] = __builtin_amdgcn_mfma_f32_16x16x32_bf16(A1, B[d][i], acc[1][i], 0, 0, 0);
    }
    if (kk + 4 < 32) {
#pragma unroll
      for (int i = 0; i < N; ++i) B[d][i] = *bptr(kk + 4, i);
    }
  }
#pragma unroll
  for (int kk = 0; kk < NBIAS; ++kk) {
    const bf16x8 Ab0 = *(const bf16x8*)(sAbp + kk * 512 + aoff);
    const bf16x8 Ab1 = *(const bf16x8*)(sAbp + NBIAS * 512 + kk * 512 + aoff);
#pragma unroll
    for (int i = 0; i < N; ++i) {
      const bf16x8 Bx = *(const bf16x8*)(BB + (uvbase + i * 16 + col) * BBW + kk * 32 + q * 8);
      acc[0][i] = __builtin_amdgcn_mfma_f32_16x16x32_bf16(Ab0, Bx, acc[0][i], 0, 0, 0);
      acc[1][i] = __builtin_amdgcn_mfma_f32_16x16x32_bf16(Ab1, Bx, acc[1][i], 0, 0, 0);
    }
  }
}

// Phase B helper: NP Q-planes share each B load; depth-4 pipeline.
template <int NP, int N, int NOFF, int NSTR, int BBW>
static __device__ __forceinline__ void mmBnp(
    const short* __restrict__ LW2T, const short* __restrict__ BB,
    const short* __restrict__ sQp, const short* __restrict__ sA1p,
    int uvbase, int col, int q, f32x4 (&acc)[NP][N]) {
  const short* lw = LW2T + (size_t)(NOFF + uvbase + col) * 64;
  const int aoff = (q * 16 + col) * 8;
  auto bptr = [&](int kk, int i) -> const bf16x8* {
    return (const bf16x8*)(lw + ((size_t)(kk >> 1) * NSTR + i * 16) * 64 +
                           ((kk & 1) * 32 + q * 8));
  };
  bf16x8 B[4][N];
#pragma unroll
  for (int d = 0; d < 4; ++d)
#pragma unroll
    for (int i = 0; i < N; ++i) B[d][i] = *bptr(d, i);
#pragma unroll
  for (int kk = 0; kk < 32; ++kk) {
    const int d = kk & 3;
    bf16x8 A[NP];
#pragma unroll
    for (int p = 0; p < NP; ++p)
      A[p] = *(const bf16x8*)(sQp + p * 16384 + kk * 512 + aoff);
#pragma unroll
    for (int i = 0; i < N; ++i)
#pragma unroll
      for (int p = 0; p < NP; ++p)
        acc[p][i] = __builtin_amdgcn_mfma_f32_16x16x32_bf16(A[p], B[d][i], acc[p][i], 0, 0, 0);
    if (kk + 4 < 32) {
#pragma unroll
      for (int i = 0; i < N; ++i) B[d][i] = *bptr(kk + 4, i);
    }
  }
  // bias: k < 16 only; same B row for all planes
#pragma unroll
  for (int i = 0; i < N; ++i) {
    const bf16x8 Bx = *(const bf16x8*)(BB + (uvbase + i * 16 + col) * BBW + q * 8);
#pragma unroll
    for (int p = 0; p < NP; ++p) {
      const bf16x8 Ap = *(const bf16x8*)(sA1p + p * 512 + aoff);
      acc[p][i] = __builtin_amdgcn_mfma_f32_16x16x32_bf16(Ap, Bx, acc[p][i], 0, 0, 0);
    }
  }
}

__global__ __launch_bounds__(512, 1) void k_main(
    const short* __restrict__ LW2T,
    const short* __restrict__ BB00, const short* __restrict__ BB11,
    const short* __restrict__ BB01, const short* __restrict__ BB10,
    const float* __restrict__ H, const float* __restrict__ H2,
    const float* __restrict__ X0, const float* __restrict__ X1,
    float* __restrict__ out) {
  constexpr float S00 = 0.0625f;                  // 1/16
  constexpr float S3 = 0.036084391824351614f;     // (1/sqrt(3))/16

  // blockIdx = slot + 8*seq, slot = (s&3) + 4*h  ->  XCD = slot:
  // XCDs 0..3 only read B-half 0, XCDs 4..7 only half 1 (2.36 MB each,
  // L2-resident).  h-split row boundaries are 128B-aligned -> no out-line
  // sharing across XCDs.
  int idx = blockIdx.x;
  int slot = idx & 7;
  int h = slot >> 2;
  int s = (slot & 3) + 4 * (idx >> 3);   // 0..127
  int b0 = s << 5;                        // 32 samples per tile
  int t = threadIdx.x;                    // 512 threads = 8 waves
  int lane = t & 63, wave = t >> 6;
  int col = lane & 15, q = lane >> 4;

  __shared__ float sH[32][66];
  __shared__ float sX0[32][17];
  __shared__ float sX1[32][51];
  __shared__ short sQ[4][32][4][16][8];   // [plane][kk][q][col][e]
  __shared__ short sAb[2][3][4][16][8];   // phase-A bias planes per group
  __shared__ short sA1[3][2][4][16][8];   // phase-B bias planes [j][g]

  for (int i = t; i < 2048; i += 512)
    sH[i >> 6][i & 63] = H[(size_t)(b0 + (i >> 6)) * 64 + (i & 63)];
  sX0[t >> 4][t & 15] = X0[(size_t)(b0 + (t >> 4)) * 16 + (t & 15)];
  for (int i = t; i < 1536; i += 512)
    sX1[i / 48][i % 48] = X1[(size_t)(b0 + i / 48) * 48 + (i % 48)];
  __syncthreads();

  // ===== build phase-A Q planes (g=0,1), sAb, sA1 =========================
  for (int i = t; i < 16384; i += 512) {
    int p = i >> 13, rem = i & 8191;
    int kk = rem >> 8, qq = (rem >> 6) & 3, cc = (rem >> 2) & 15, e2 = (rem & 3) << 1;
    int k = kk * 32 + qq * 8 + e2;
    int w = k >> 6, c = k & 63;
    float xw = sX0[p * 16 + cc][w];
    unsigned lo = (unsigned short)f2bf(sH[p * 16 + cc][c] * xw);
    unsigned hi = (unsigned short)f2bf(sH[p * 16 + cc][c + 1] * xw);
    *(unsigned*)&sQ[p][kk][qq][cc][e2] = lo | (hi << 16);
  }
  for (int i = t; i < 3072; i += 512) {   // sAb
    int g = (i >= 1536), rem = i - (g ? 1536 : 0);
    int kk = rem >> 9, r2 = rem & 511;
    int qq = r2 >> 7, cc = (r2 >> 3) & 15, e = r2 & 7;
    int k = kk * 32 + qq * 8 + e;
    float v = 0.0f;
    if (k < 64) v = H2[(size_t)(b0 + g * 16 + cc) * 64 + k];
    else if (k < 80) v = sX0[g * 16 + cc][k - 64];
    else if (k == 80) v = 1.0f;
    sAb[g][kk][qq][cc][e] = f2bf(v);
  }
  for (int i = t; i < 3072; i += 512) {   // sA1 (all 3 j)
    int j = i >> 10, rem = i & 1023;
    int g = rem >> 9, r2 = rem & 511;
    int qq = r2 >> 7, cc = (r2 >> 3) & 15, e = r2 & 7;
    int k = qq * 8 + e;
    sA1[j][g][qq][cc][e] = (k < 16) ? f2bf(sX1[g * 16 + cc][k * 3 + j]) : (short)0;
  }
  __syncthreads();

  // ===== phase A: path00 (uv-half 512, wave owns 64) ======================
  {
    int uvbase = h * 512 + wave * 64;
    f32x4 acc[2][4] = {};
    mmA2<4, 0, 1024, 3, 96>(LW2T, BB00, &sQ[0][0][0][0][0], &sAb[0][0][0][0][0],
                            uvbase, col, q, acc);
#pragma unroll
    for (int g = 0; g < 2; ++g)
#pragma unroll
      for (int i = 0; i < 4; ++i)
#pragma unroll
        for (int ii = 0; ii < 4; ++ii) {
          size_t ob = (size_t)(b0 + g * 16 + q * 4 + ii) * 6400;
          int uv = uvbase + i * 16 + col;
          st_nt(acc[g][i][ii] * S00, &out[ob + (uv >> 5) * 80 + (uv & 31)]);
        }
  }
  // path11 (uv-half 128, wave owns 16)
  {
    int uvbase = h * 128 + wave * 16;
    f32x4 acc[2][1] = {};
    mmA2<1, 16384, 256, 3, 96>(LW2T, BB11, &sQ[0][0][0][0][0], &sAb[0][0][0][0][0],
                               uvbase, col, q, acc);
#pragma unroll
    for (int g = 0; g < 2; ++g)
#pragma unroll
      for (int ii = 0; ii < 4; ++ii) {
        size_t ob = (size_t)(b0 + g * 16 + q * 4 + ii) * 6400;
        int uv = uvbase + col;
        float val = acc[g][0][ii] * S3;
        int u = uv >> 4, v = uv & 15;
        float* p = out + ob + (size_t)(32 + 3 * u) * 80 + (32 + 3 * v);
        st_nt(val, p + 0);   st_nt(0.f, p + 1);   st_nt(0.f, p + 2);
        st_nt(0.f, p + 80);  st_nt(val, p + 81);  st_nt(0.f, p + 82);
        st_nt(0.f, p + 160); st_nt(0.f, p + 161); st_nt(val, p + 162);
      }
  }

  // ===== phase B pass 1: planes (j,g) = (0,0),(0,1),(1,0),(1,1) ===========
  __syncthreads();
  for (int i = t; i < 32768; i += 512) {
    int p = i >> 13, rem = i & 8191;
    int j = p >> 1, g = p & 1;
    int kk = rem >> 8, qq = (rem >> 6) & 3, cc = (rem >> 2) & 15, e2 = (rem & 3) << 1;
    int k = kk * 32 + qq * 8 + e2;
    int w = k >> 6, c = k & 63;
    float xw = sX1[g * 16 + cc][w * 3 + j];
    unsigned lo = (unsigned short)f2bf(sH[g * 16 + cc][c] * xw);
    unsigned hi = (unsigned short)f2bf(sH[g * 16 + cc][c + 1] * xw);
    *(unsigned*)&sQ[p][kk][qq][cc][e2] = lo | (hi << 16);
  }
  __syncthreads();
  {
    int uvbase = h * 256 + wave * 32;
    {
      f32x4 acc[4][2] = {};
      mmBnp<4, 2, 20480, 512, 32>(LW2T, BB01, &sQ[0][0][0][0][0],
                                  &sA1[0][0][0][0][0], uvbase, col, q, acc);
#pragma unroll
      for (int p = 0; p < 4; ++p)
#pragma unroll
        for (int i = 0; i < 2; ++i)
#pragma unroll
          for (int ii = 0; ii < 4; ++ii) {
            int j = p >> 1, g = p & 1;
            size_t ob = (size_t)(b0 + g * 16 + q * 4 + ii) * 6400;
            int uv = uvbase + i * 16 + col;
            st_nt(acc[p][i][ii] * S3, &out[ob + (uv >> 4) * 80 + 32 + 3 * (uv & 15) + j]);
          }
    }
    {
      f32x4 acc[4][2] = {};
      mmBnp<4, 2, 28672, 512, 32>(LW2T, BB10, &sQ[0][0][0][0][0],
                                  &sA1[0][0][0][0][0], uvbase, col, q, acc);
#pragma unroll
      for (int p = 0; p < 4; ++p)
#pragma unroll
        for (int i = 0; i < 2; ++i)
#pragma unroll
          for (int ii = 0; ii < 4; ++ii) {
            int j = p >> 1, g = p & 1;
            size_t ob = (size_t)(b0 + g * 16 + q * 4 + ii) * 6400;
            int uv = uvbase + i * 16 + col;
            st_nt(acc[p][i][ii] * S3,
                  &out[ob + (size_t)(32 + 3 * (uv >> 5) + j) * 80 + (uv & 31)]);
          }
    }
  }

  // ===== phase B pass 2: planes g = 0,1 at j = 2 ==========================
  __syncthreads();
  for (int i = t; i < 16384; i += 512) {
    int g = i >> 13, rem = i & 8191;
    int kk = rem >> 8, qq = (rem >> 6) & 3, cc = (rem >> 2) & 15, e2 = (rem & 3) << 1;
    int k = kk * 32 + qq * 8 + e2;
    int w = k >> 6, c = k & 63;
    float xw = sX1[g * 16 + cc][w * 3 + 2];
    unsigned lo = (unsigned short)f2bf(sH[g * 16 + cc][c] * xw);
    unsigned hi = (unsigned short)f2bf(sH[g * 16 + cc][c + 1] * xw);
    *(unsigned*)&sQ[g][kk][qq][cc][e2] = lo | (hi << 16);
  }
  __syncthreads();
  {
    int uvbase = h * 256 + wave * 32;
    {
      f32x4 acc[2][2] = {};
      mmBnp<2, 2, 20480, 512, 32>(LW2T, BB01, &sQ[0][0][0][0][0],
                                  &sA1[2][0][0][0][0], uvbase, col, q, acc);
#pragma unroll
      for (int g = 0; g < 2; ++g)
#pragma unroll
        for (int i = 0; i < 2; ++i)
#pragma unroll
          for (int ii = 0; ii < 4; ++ii) {
            size_t ob = (size_t)(b0 + g * 16 + q * 4 + ii) * 6400;
            int uv = uvbase + i * 16 + col;
            st_nt(acc[g][i][ii] * S3, &out[ob + (uv >> 4) * 80 + 32 + 3 * (uv & 15) + 2]);
          }
    }
    {
      f32x4 acc[2][2] = {};
      mmBnp<2, 2, 28672, 512, 32>(LW2T, BB10, &sQ[0][0][0][0][0],
                                  &sA1[2][0][0][0][0], uvbase, col, q, acc);
#pragma unroll
      for (int g = 0; g < 2; ++g)
#pragma unroll
        for (int i = 0; i < 2; ++i)
#pragma unroll
          for (int ii = 0; ii < 4; ++ii) {
            size_t ob = (size_t)(b0 + g * 16 + q * 4 + ii) * 6400;
            int uv = uvbase + i * 16 + col;
            st_nt(acc[g][i][ii] * S3,
                  &out[ob + (size_t)(32 + 3 * (uv >> 5) + 2) * 80 + (uv & 31)]);
          }
    }
  }
}

// ---------------------------------------------------------------------------
extern "C" void kernel_launch(void* const* d_in, const int* in_sizes, int n_in,
                              void* d_out, int out_size, void* d_ws, size_t ws_size,
                              hipStream_t stream) {
  const float* feat = (const float*)d_in[0];
  const float* ne   = (const float*)d_in[1];
  const float* W0   = (const float*)d_in[2];
  const float* W1   = (const float*)d_in[3];
  const float* lw1  = (const float*)d_in[4];
  const float* lb1  = (const float*)d_in[5];
  const float* lw2  = (const float*)d_in[6];
  const float* lb2  = (const float*)d_in[7];
  const float* bw1  = (const float*)d_in[8];
  const float* bb1  = (const float*)d_in[9];
  const float* bw2  = (const float*)d_in[10];
  const float* bb2  = (const float*)d_in[11];

  char* ws = (char*)d_ws;
  short* LW2T = (short*)ws; ws += (size_t)36864 * 64 * 2;   // 4.72 MB
  short* BB00 = (short*)ws; ws += (size_t)1024 * 96 * 2;
  short* BB11 = (short*)ws; ws += (size_t)256 * 96 * 2;
  short* BB01 = (short*)ws; ws += (size_t)512 * 32 * 2;
  short* BB10 = (short*)ws; ws += (size_t)512 * 32 * 2;
  float* H  = (float*)ws;   ws += (size_t)4096 * 64 * 4;
  float* H2 = (float*)ws;   ws += (size_t)4096 * 64 * 4;
  float* X0 = (float*)ws;   ws += (size_t)4096 * 16 * 4;
  float* X1 = (float*)ws;   ws += (size_t)4096 * 48 * 4;
  (void)ws_size; (void)in_sizes; (void)n_in; (void)out_size;

  hipLaunchKernelGGL(k_transpose, dim3(576), dim3(256), 0, stream, lw2, LW2T);
  hipLaunchKernelGGL(k_bias, dim3(9), dim3(256), 0, stream, bw2, lb2, bb2,
                     BB00, BB11, BB01, BB10);
  hipLaunchKernelGGL(k_samples, dim3(4096), dim3(192), 0, stream,
                     feat, ne, W0, W1, lw1, lb1, bw1, bb1, H, H2, X0, X1);
  hipLaunchKernelGGL(k_main, dim3(256), dim3(512), 0, stream,
                     LW2T, BB00, BB11, BB01, BB10, H, H2, X0, X1, (float*)d_out);
}